// Round 1
// baseline (6070.417 us; speedup 1.0000x reference)
//
#include <hip/hip_runtime.h>
#include <math.h>

static __device__ __forceinline__ float sigf(float x){ return 1.0f/(1.0f+expf(-x)); }

// ---------------------------------------------------------------------------
// Generic tiled f32 GEMM: C[M x N](ldc) = act( A[M x K](lda) @ Bw[K x N] + bias ) * rowscale
// A row for logical row r: permA ? ((r&1023)*63 + (r>>10) + aRowAdd) : r
//   (maps node-major row (node,b) -> b-major input row b*63 + node_global)
// act: 0 = none, 1 = tanh.  BM=128, BK=16, 256 threads, TM=8 rows/thread.
// ---------------------------------------------------------------------------
template<int BN, int TN>
__launch_bounds__(256)
__global__ void gemm_f32(const float* __restrict__ A, const float* __restrict__ Bw,
                         float* __restrict__ Cmat,
                         const float* __restrict__ bias,
                         const float* __restrict__ rowscale,
                         int M, int N, int K, int lda, int ldc,
                         int aRowAdd, int permA, int act)
{
    constexpr int BM = 128, BK = 16, TM = 8;
    __shared__ float As[BK][BM];
    __shared__ float Bs[BK][BN];
    const int tid = threadIdx.x;
    const int tx = tid & 15, ty = tid >> 4;
    const int r0 = blockIdx.x * BM, c0 = blockIdx.y * BN;

    float acc[TM][TN];
#pragma unroll
    for (int i = 0; i < TM; i++)
#pragma unroll
        for (int j = 0; j < TN; j++) acc[i][j] = 0.f;

    // A staging: 128 rows x 16 k, thread covers row am, k-groups akg*8..+7 (2 float4)
    const int am  = tid & 127;
    const int akg = tid >> 7;          // 0..1
    const int rrA = r0 + am;
    long arow = permA ? (long)((rrA & 1023) * 63 + (rrA >> 10) + aRowAdd) : (long)rrA;
    const float* ap = A + arow * (long)lda;

    // B staging: BK x BN, float4 per slot
    constexpr int NG = BN / 4;         // n-groups
    constexpr int KR = 256 / NG;       // k-rows covered per pass
    const int bn0 = (tid % NG) * 4;
    const int bkr = tid / NG;

    for (int kt = 0; kt < K; kt += BK) {
        // stage A (transposed into As[k][m])
#pragma unroll
        for (int v = 0; v < 2; v++) {
            int kk = akg * 8 + v * 4;
            int k  = kt + kk;
            float4 val;
            if (k + 3 < K) {
                val = *(const float4*)(ap + k);
            } else {
                float t0 = (k + 0 < K) ? ap[k + 0] : 0.f;
                float t1 = (k + 1 < K) ? ap[k + 1] : 0.f;
                float t2 = (k + 2 < K) ? ap[k + 2] : 0.f;
                float t3 = (k + 3 < K) ? ap[k + 3] : 0.f;
                val = make_float4(t0, t1, t2, t3);
            }
            As[kk + 0][am] = val.x; As[kk + 1][am] = val.y;
            As[kk + 2][am] = val.z; As[kk + 3][am] = val.w;
        }
        // stage B
#pragma unroll
        for (int p = 0; p < BK / KR; p++) {
            int kk = bkr + p * KR;
            int gk = kt + kk;
            float4 val = make_float4(0.f, 0.f, 0.f, 0.f);
            if (gk < K) val = *(const float4*)(Bw + (long)gk * N + c0 + bn0);
            *(float4*)&Bs[kk][bn0] = val;
        }
        __syncthreads();
#pragma unroll
        for (int k = 0; k < BK; k++) {
            float a[TM], b[TN];
#pragma unroll
            for (int i = 0; i < TM; i++) a[i] = As[k][ty * TM + i];
#pragma unroll
            for (int j = 0; j < TN; j++) b[j] = Bs[k][tx * TN + j];
#pragma unroll
            for (int i = 0; i < TM; i++)
#pragma unroll
                for (int j = 0; j < TN; j++) acc[i][j] = fmaf(a[i], b[j], acc[i][j]);
        }
        __syncthreads();
    }

#pragma unroll
    for (int i = 0; i < TM; i++) {
        int rr = r0 + ty * TM + i;
        float rs = 1.f;
        if (rowscale) rs = rowscale[(rr & 1023) * 63 + (rr >> 10) + aRowAdd];
#pragma unroll
        for (int j = 0; j < TN; j++) {
            int cc = c0 + tx * TN + j;
            float v = acc[i][j];
            if (bias) v += bias[cc];
            if (act == 1) v = tanhf(v);
            v *= rs;
            Cmat[(long)rr * ldc + cc] = v;
        }
    }
}

// ---------------------------------------------------------------------------
// Fused gate GEMM + LSTM cell.
// Block computes rows [r0,r0+64), cols [c0,c0+64) for ALL FOUR gates (i,f,g,o),
// then does the cell update in-register. A = concat(xl[.,640], h0[.,256]).
// gates = xl@W_ih^T + b_ih + h0@W_hh^T + b_hh ; c = sig(f)*c0 + sig(i)*tanh(g);
// h = sig(o)*tanh(c). c0 = 0 (level 0) or 0.5*(child cells sum).
// ---------------------------------------------------------------------------
__launch_bounds__(256)
__global__ void gates_lstm(const float* __restrict__ xl, const float* __restrict__ h0,
                           const float* __restrict__ W_ih, const float* __restrict__ b_ih,
                           const float* __restrict__ W_hh, const float* __restrict__ b_hh,
                           const float* __restrict__ Cprev,   // full C buffer, null at level 0
                           float* __restrict__ Hbuf, float* __restrict__ Cbuf,
                           int offCur, int offPrev, int Ktot)
{
    constexpr int BK = 16;
    __shared__ float As[BK][64];
    __shared__ float Bs[4][BK][64];
    __shared__ float bias_s[4][64];
    const int tid = threadIdx.x;
    const int tx = tid & 15, ty = tid >> 4;
    const int r0 = blockIdx.x * 64, c0 = blockIdx.y * 64;

    {
        int g = tid >> 6, j = tid & 63;
        bias_s[g][j] = b_ih[g * 256 + c0 + j] + b_hh[g * 256 + c0 + j];
    }

    float acc[4][4][4];
#pragma unroll
    for (int g = 0; g < 4; g++)
#pragma unroll
        for (int r = 0; r < 4; r++)
#pragma unroll
            for (int c = 0; c < 4; c++) acc[g][r][c] = 0.f;

    const int am = tid & 63, akg = tid >> 6;   // 64 rows x 4 k-groups
    const long arowl = r0 + am;

    for (int kt = 0; kt < Ktot; kt += BK) {
        int k = kt + akg * 4;
        {
            float4 v;
            if (k < 640) v = *(const float4*)(xl + arowl * 640 + k);
            else         v = *(const float4*)(h0 + arowl * 256 + (k - 640));
            int kk = akg * 4;
            As[kk + 0][am] = v.x; As[kk + 1][am] = v.y;
            As[kk + 2][am] = v.z; As[kk + 3][am] = v.w;
        }
#pragma unroll
        for (int g = 0; g < 4; g++) {
            long nrow = g * 256 + c0 + am;
            float4 v;
            if (k < 640) v = *(const float4*)(W_ih + nrow * 640 + k);
            else         v = *(const float4*)(W_hh + nrow * 256 + (k - 640));
            int kk = akg * 4;
            Bs[g][kk + 0][am] = v.x; Bs[g][kk + 1][am] = v.y;
            Bs[g][kk + 2][am] = v.z; Bs[g][kk + 3][am] = v.w;
        }
        __syncthreads();
#pragma unroll
        for (int k2 = 0; k2 < BK; k2++) {
            float a[4];
#pragma unroll
            for (int r = 0; r < 4; r++) a[r] = As[k2][ty * 4 + r];
#pragma unroll
            for (int g = 0; g < 4; g++) {
                float b[4];
#pragma unroll
                for (int c = 0; c < 4; c++) b[c] = Bs[g][k2][tx * 4 + c];
#pragma unroll
                for (int r = 0; r < 4; r++)
#pragma unroll
                    for (int c = 0; c < 4; c++)
                        acc[g][r][c] = fmaf(a[r], b[c], acc[g][r][c]);
            }
        }
        __syncthreads();
    }

#pragma unroll
    for (int r = 0; r < 4; r++) {
        int row = r0 + ty * 4 + r;           // level-local row
        int nd = row >> 10, bb = row & 1023;
#pragma unroll
        for (int c = 0; c < 4; c++) {
            int col = c0 + tx * 4 + c;
            float iv = acc[0][r][c] + bias_s[0][tx * 4 + c];
            float fv = acc[1][r][c] + bias_s[1][tx * 4 + c];
            float gv = acc[2][r][c] + bias_s[2][tx * 4 + c];
            float ov = acc[3][r][c] + bias_s[3][tx * 4 + c];
            float c0v = 0.f;
            if (Cprev) {
                long ch = ((long)(offPrev + nd * 2) * 1024 + bb) * 256 + col;
                c0v = 0.5f * (Cprev[ch] + Cprev[ch + 1024 * 256]);
            }
            float cv = sigf(fv) * c0v + sigf(iv) * tanhf(gv);
            float hv = sigf(ov) * tanhf(cv);
            long orow = ((long)offCur * 1024 + row) * 256 + col;
            Hbuf[orow] = hv;
            Cbuf[orow] = cv;
        }
    }
}

// ---------------------------------------------------------------------------
// Attention logits: one wave per descendant row dr (= H row index, levels 0..l-1).
// logit = sum_j tanh(E[dr][j] + xext[target][j]) * W_a[j], written to
// Lbuf[(i*m + d)*1024 + b] where (i,d) locate it in the target's softmax group.
// ---------------------------------------------------------------------------
__launch_bounds__(256)
__global__ void attn_logits(const float* __restrict__ E, const float* __restrict__ xext,
                            const float* __restrict__ W_a, float* __restrict__ Lbuf,
                            int level, int rows, int m)
{
    const int wv = threadIdx.x >> 6, ln = threadIdx.x & 63;
    const long dr = (long)blockIdx.x * 4 + wv;
    if (dr >= rows) return;
    const int g = (int)(dr >> 10), bb = (int)(dr & 1023);
    int lp, node;
    if      (g < 32) { lp = 0; node = g;      }
    else if (g < 48) { lp = 1; node = g - 32; }
    else if (g < 56) { lp = 2; node = g - 48; }
    else if (g < 60) { lp = 3; node = g - 56; }
    else             { lp = 4; node = g - 60; }
    const int shift  = level - lp;
    const int i      = node >> shift;
    const int within = node & ((1 << shift) - 1);
    const int d      = ((2 << level) - (2 << shift)) + within;

    float e = E[dr * 64 + ln] + xext[((long)i * 1024 + bb) * 64 + ln];
    float v = tanhf(e) * W_a[ln];
#pragma unroll
    for (int s = 32; s; s >>= 1) v += __shfl_xor(v, s);
    if (ln == 0) Lbuf[((long)(i * m + d)) * 1024 + bb] = v;
}

// ---------------------------------------------------------------------------
// Softmax over the m descendants + weighted pooling. One block per (i, b).
// pooled[i*1024+b][h] = sum_d softmax(logits)_d * H[descrow(d)][h]
// ---------------------------------------------------------------------------
__launch_bounds__(256)
__global__ void attn_pool(const float* __restrict__ Lbuf, const float* __restrict__ Hbuf,
                          float* __restrict__ pooled, int level, int m)
{
    const int blk = blockIdx.x;            // i*1024 + b
    const int i = blk >> 10, bb = blk & 1023;
    const int tid = threadIdx.x;
    __shared__ float raw[64];
    __shared__ float wsm[64];
    if (tid < m) raw[tid] = Lbuf[((long)(i * m + tid)) * 1024 + bb];
    __syncthreads();
    if (tid == 0) {
        float mx = -1e30f;
        for (int d = 0; d < m; d++) mx = fmaxf(mx, raw[d]);
        float s = 0.f;
        for (int d = 0; d < m; d++) { float e = expf(raw[d] - mx); wsm[d] = e; s += e; }
        float inv = 1.f / s;
        for (int d = 0; d < m; d++) wsm[d] *= inv;
    }
    __syncthreads();
    float accv = 0.f;
    const int h = tid;                     // 0..255
    int cum = 0;
    for (int lp = 0; lp < level; lp++) {
        int sz = 1 << (level - lp);
        int base = 64 - (64 >> lp);        // OFFSETS[lp]
        for (int q = 0; q < sz; q++) {
            long row = (long)(base + i * sz + q) * 1024 + bb;
            accv = fmaf(wsm[cum + q], Hbuf[row * 256 + h], accv);
        }
        cum += sz;
    }
    pooled[(long)blk * 256 + h] = accv;
}

// ---------------------------------------------------------------------------
// Output heads: cost/card MLPs on the root hidden. One block per batch b.
// ---------------------------------------------------------------------------
__launch_bounds__(256)
__global__ void heads_kernel(const float* __restrict__ Hbuf,
                             const float* __restrict__ W_c1, const float* __restrict__ b_c1,
                             const float* __restrict__ W_c2, const float* __restrict__ b_c2,
                             const float* __restrict__ W_c3, const float* __restrict__ b_c3,
                             const float* __restrict__ W_d1, const float* __restrict__ b_d1,
                             const float* __restrict__ W_d2, const float* __restrict__ b_d2,
                             const float* __restrict__ W_d3, const float* __restrict__ b_d3,
                             float* __restrict__ out)
{
    const int bb = blockIdx.x, tid = threadIdx.x;
    __shared__ float root[256];
    __shared__ float t1[128];
    __shared__ float t2[128];
    __shared__ float red[256];
    root[tid] = Hbuf[((long)62 * 1024 + bb) * 256 + tid];
    __syncthreads();
    for (int head = 0; head < 2; head++) {
        const float* w1  = head ? W_d1 : W_c1;
        const float* bi1 = head ? b_d1 : b_c1;
        const float* w2  = head ? W_d2 : W_c2;
        const float* bi2 = head ? b_d2 : b_c2;
        const float* w3  = head ? W_d3 : W_c3;
        const float* bi3 = head ? b_d3 : b_c3;
        if (tid < 128) {
            float s = bi1[tid];
            for (int k = 0; k < 256; k++) s = fmaf(root[k], w1[k * 128 + tid], s);
            t1[tid] = fmaxf(s, 0.f);
        }
        __syncthreads();
        if (tid < 128) {
            float s = bi2[tid];
            for (int k = 0; k < 128; k++) s = fmaf(t1[k], w2[k * 128 + tid], s);
            t2[tid] = fmaxf(s, 0.f);
        }
        __syncthreads();
        red[tid] = (tid < 128) ? t2[tid] * w3[tid] : 0.f;
        __syncthreads();
        for (int s = 128; s; s >>= 1) { if (tid < s) red[tid] += red[tid + s]; __syncthreads(); }
        if (tid == 0) out[head * 1024 + bb] = sigf(red[0] + bi3[0]);
        __syncthreads();
    }
}

// ---------------------------------------------------------------------------
extern "C" void kernel_launch(void* const* d_in, const int* in_sizes, int n_in,
                              void* d_out, int out_size, void* d_ws, size_t ws_size,
                              hipStream_t stream)
{
    (void)in_sizes; (void)n_in; (void)out_size;
    const float* op       = (const float*)d_in[0];
    const float* feat     = (const float*)d_in[1];
    const float* cond1    = (const float*)d_in[2];
    const float* cond2    = (const float*)d_in[3];
    const float* bitmap   = (const float*)d_in[4];
    const float* has_cond = (const float*)d_in[5];
    const float* W_op     = (const float*)d_in[6];
    const float* b_op     = (const float*)d_in[7];
    const float* W_feat   = (const float*)d_in[8];
    const float* b_feat   = (const float*)d_in[9];
    const float* W_pred   = (const float*)d_in[10];
    const float* b_pred   = (const float*)d_in[11];
    const float* W_bm     = (const float*)d_in[12];
    const float* b_bm     = (const float*)d_in[13];
    const float* W_ih     = (const float*)d_in[14];
    const float* b_ih     = (const float*)d_in[15];
    const float* W_hh     = (const float*)d_in[16];
    const float* b_hh     = (const float*)d_in[17];
    const float* W_wh     = (const float*)d_in[18];
    const float* W_ext    = (const float*)d_in[19];
    const float* W_a      = (const float*)d_in[20];
    const float* W_ht     = (const float*)d_in[21];
    const float* b_ht     = (const float*)d_in[22];
    const float* W_c1     = (const float*)d_in[23];
    const float* b_c1     = (const float*)d_in[24];
    const float* W_c2     = (const float*)d_in[25];
    const float* b_c2     = (const float*)d_in[26];
    const float* W_c3     = (const float*)d_in[27];
    const float* b_c3     = (const float*)d_in[28];
    const float* W_d1     = (const float*)d_in[29];
    const float* b_d1     = (const float*)d_in[30];
    const float* W_d2     = (const float*)d_in[31];
    const float* b_d2     = (const float*)d_in[32];
    const float* W_d3     = (const float*)d_in[33];
    const float* b_d3     = (const float*)d_in[34];
    float* out = (float*)d_out;

    // workspace layout (floats), node-major rows: row = node_global*1024 + b
    float* ws     = (float*)d_ws;
    float* xl     = ws;                                 // 32*1024*640  (per-level x slice)
    float* Hbuf   = xl     + (size_t)32 * 1024 * 640;   // 63*1024*256  (all hiddens)
    float* Cbuf   = Hbuf   + (size_t)63 * 1024 * 256;   // 63*1024*256  (all cells)
    float* Ebuf   = Cbuf   + (size_t)63 * 1024 * 256;   // 62*1024*64   (H @ W_wh, levels 0..4)
    float* xext   = Ebuf   + (size_t)62 * 1024 * 64;    // 16*1024*64
    float* pooled = xext   + (size_t)16 * 1024 * 64;    // 16*1024*256
    float* h0     = pooled + (size_t)16 * 1024 * 256;   // 16*1024*256
    float* Lbuf   = h0     + (size_t)16 * 1024 * 256;   // 65536
    size_t needed = ((size_t)(Lbuf - ws) + 65536) * sizeof(float);
    if (ws_size < needed) return;  // insufficient scratch: fail validation cleanly

    for (int l = 0; l < 6; l++) {
        const int n   = 32 >> l;
        const int off = 64 - (64 >> l);     // OFFSETS[l]
        const int M   = n * 1024;
        const int m   = (2 << l) - 2;

        // x projections for this level's nodes -> xl[M x 640]
        gemm_f32<128, 8><<<dim3(M / 128, 1), 256, 0, stream>>>(op,     W_op,   xl + 0,   b_op,   nullptr,  M, 128, 32,   32,   640, off, 1, 0);
        gemm_f32<128, 8><<<dim3(M / 128, 1), 256, 0, stream>>>(feat,   W_feat, xl + 128, b_feat, nullptr,  M, 128, 64,   64,   640, off, 1, 0);
        gemm_f32<128, 8><<<dim3(M / 128, 1), 256, 0, stream>>>(cond1,  W_pred, xl + 256, b_pred, nullptr,  M, 128, 256,  256,  640, off, 1, 0);
        gemm_f32<128, 8><<<dim3(M / 128, 1), 256, 0, stream>>>(cond2,  W_pred, xl + 384, b_pred, nullptr,  M, 128, 256,  256,  640, off, 1, 0);
        gemm_f32<128, 8><<<dim3(M / 128, 1), 256, 0, stream>>>(bitmap, W_bm,   xl + 512, b_bm,   has_cond, M, 128, 1000, 1000, 640, off, 1, 0);

        if (l > 0) {
            // xext = xl @ W_ext   [M x 64]
            gemm_f32<64, 4><<<dim3(M / 128, 1), 256, 0, stream>>>(xl, W_ext, xext, nullptr, nullptr, M, 64, 640, 640, 64, 0, 0, 0);
            // logits over all descendant rows (levels 0..l-1)
            int rows = off * 1024;
            attn_logits<<<rows / 4, 256, 0, stream>>>(Ebuf, xext, W_a, Lbuf, l, rows, m);
            // softmax + pooling
            attn_pool<<<M, 256, 0, stream>>>(Lbuf, Hbuf, pooled, l, m);
            // h0 = tanh(pooled @ W_ht + b_ht)
            gemm_f32<128, 8><<<dim3(M / 128, 2), 256, 0, stream>>>(pooled, W_ht, h0, b_ht, nullptr, M, 256, 256, 256, 256, 0, 0, 1);
        }

        // fused gates + LSTM cell update
        const int Ktot    = (l > 0) ? 896 : 640;
        const int offPrev = (l > 0) ? (64 - (64 >> (l - 1))) : 0;
        gates_lstm<<<dim3(M / 64, 4), 256, 0, stream>>>(xl, h0, W_ih, b_ih, W_hh, b_hh,
                                                        (l > 0) ? Cbuf : nullptr,
                                                        Hbuf, Cbuf, off, offPrev, Ktot);

        if (l < 5) {
            // E rows for this level (used as descendants by later levels)
            gemm_f32<64, 4><<<dim3(M / 128, 1), 256, 0, stream>>>(Hbuf + (size_t)off * 1024 * 256, W_wh,
                                                                  Ebuf + (size_t)off * 1024 * 64,
                                                                  nullptr, nullptr, M, 64, 256, 256, 64, 0, 0, 0);
        }
    }

    heads_kernel<<<1024, 256, 0, stream>>>(Hbuf, W_c1, b_c1, W_c2, b_c2, W_c3, b_c3,
                                           W_d1, b_d1, W_d2, b_d2, W_d3, b_d3, out);
}

// Round 2
// 1392.255 us; speedup vs baseline: 4.3601x; 4.3601x over previous
//
#include <hip/hip_runtime.h>
#include <math.h>

typedef unsigned short u16;
typedef __bf16 bf16x8 __attribute__((ext_vector_type(8)));
typedef float f32x4 __attribute__((ext_vector_type(4)));

static __device__ __forceinline__ float sigf(float x){ return 1.0f/(1.0f+expf(-x)); }
static __device__ __forceinline__ u16 f2bf(float f){
    unsigned u = __builtin_bit_cast(unsigned, f);
    unsigned r = u + 0x7FFFu + ((u >> 16) & 1u);
    return (u16)(r >> 16);
}
static __device__ __forceinline__ float b2f(u16 s){
    unsigned u = ((unsigned)s) << 16;
    return __builtin_bit_cast(float, u);
}

// ---------------------------------------------------------------------------
// Weight prep: Wt[n][k] = bf16(W[k][n]), zero-padded to Kpad.
// ---------------------------------------------------------------------------
__global__ void prep_w(const float* __restrict__ W, u16* __restrict__ Wt,
                       int K, int N, int Kpad)
{
    int idx = blockIdx.x * 256 + threadIdx.x;
    if (idx >= N * Kpad) return;
    int n = idx / Kpad, k = idx - n * Kpad;
    Wt[idx] = (k < K) ? f2bf(W[(long)k * N + n]) : (u16)0;
}

// Wt_g[n][k]: k<640 from W_ih[n][k] (already [N][K]), else W_hh[n][k-640]
__global__ void prep_g(const float* __restrict__ W_ih, const float* __restrict__ W_hh,
                       u16* __restrict__ Wt)
{
    int idx = blockIdx.x * 256 + threadIdx.x;   // 1024*896
    int n = idx / 896, k = idx - n * 896;
    float v = (k < 640) ? W_ih[(long)n * 640 + k] : W_hh[(long)n * 256 + (k - 640)];
    Wt[idx] = f2bf(v);
}

// ---------------------------------------------------------------------------
// Generic MFMA GEMM: C[M x N] = act(A @ Bt^T + bias) * rowscale
//   A: f32 (converted during LDS staging) or bf16, row-major, lda
//   Bt: bf16 [N][Kpad] (pre-transposed weights)
//   tile 128 x BN, BK=32, 256 threads (4 waves), mfma_f32_16x16x32_bf16
//   permA: logical row r -> input row (r&1023)*63 + (r>>10)   (node-major->b-major)
// ---------------------------------------------------------------------------
template<bool AF32, int BN>
__launch_bounds__(256)
__global__ void gemm_bf16(const void* __restrict__ Aptr, const u16* __restrict__ Bt,
                          void* __restrict__ Cout, const float* __restrict__ bias,
                          const float* __restrict__ rowscale,
                          int Kreal, int Kpad, int lda, int ldc,
                          int permA, int act, int outBF16)
{
    constexpr int BM = 128, LDT = 40;             // LDS row stride (shorts), 80B: conflict-free-ish
    constexpr int WM = (BN == 128) ? 2 : 4;       // wave grid
    constexpr int MI = BM / WM / 16;              // 4 or 2
    constexpr int NI = (BN == 128) ? 4 : 4;
    __shared__ u16 As[BM * LDT];
    __shared__ u16 Bs[BN * LDT];

    const int tid = threadIdx.x;
    const int lane = tid & 63, wv = tid >> 6;
    const int r0 = blockIdx.x * BM, c0 = blockIdx.y * BN;
    const int wr = (wv % WM) * (BM / WM);
    const int wc = (wv / WM) * 64;
    const int l15 = lane & 15, q8 = (lane >> 4) * 8;

    f32x4 acc[MI][NI];
#pragma unroll
    for (int i = 0; i < MI; i++)
#pragma unroll
        for (int j = 0; j < NI; j++) acc[i][j] = (f32x4){0.f, 0.f, 0.f, 0.f};

    for (int kt = 0; kt < Kpad; kt += 32) {
        // ---- stage A tile (128 x 32)
        if (AF32) {
            const float* Ag = (const float*)Aptr;
#pragma unroll
            for (int p = 0; p < 4; p++) {
                int v = tid + p * 256;
                int row = v >> 3, kc = (v & 7) * 4;
                long ar = r0 + row;
                long arow = permA ? ((ar & 1023) * 63 + (ar >> 10)) : ar;
                int k = kt + kc;
                float4 val;
                if (k + 4 <= Kreal) {
                    val = *(const float4*)(Ag + arow * (long)lda + k);
                } else {
                    val.x = (k + 0 < Kreal) ? Ag[arow * (long)lda + k + 0] : 0.f;
                    val.y = (k + 1 < Kreal) ? Ag[arow * (long)lda + k + 1] : 0.f;
                    val.z = (k + 2 < Kreal) ? Ag[arow * (long)lda + k + 2] : 0.f;
                    val.w = (k + 3 < Kreal) ? Ag[arow * (long)lda + k + 3] : 0.f;
                }
                ushort4 o; o.x = f2bf(val.x); o.y = f2bf(val.y); o.z = f2bf(val.z); o.w = f2bf(val.w);
                *(ushort4*)&As[row * LDT + kc] = o;
            }
        } else {
            const u16* Ag = (const u16*)Aptr;
#pragma unroll
            for (int p = 0; p < 2; p++) {
                int v = tid + p * 256;
                int row = v >> 2, kc = (v & 3) * 8;
                long ar = r0 + row;
                *(int4*)&As[row * LDT + kc] = *(const int4*)(Ag + ar * (long)lda + kt + kc);
            }
        }
        // ---- stage B tile (BN x 32), bf16 [N][Kpad]
        constexpr int BCH = BN * 4 / 256;
#pragma unroll
        for (int p = 0; p < BCH; p++) {
            int v = tid + p * 256;
            int row = v >> 2, kc = (v & 3) * 8;
            *(int4*)&Bs[row * LDT + kc] = *(const int4*)(Bt + (long)(c0 + row) * Kpad + kt + kc);
        }
        __syncthreads();

        bf16x8 af[MI], bfr[NI];
#pragma unroll
        for (int mi = 0; mi < MI; mi++)
            af[mi] = *reinterpret_cast<const bf16x8*>(&As[(wr + mi * 16 + l15) * LDT + q8]);
#pragma unroll
        for (int ni = 0; ni < NI; ni++)
            bfr[ni] = *reinterpret_cast<const bf16x8*>(&Bs[(wc + ni * 16 + l15) * LDT + q8]);
#pragma unroll
        for (int mi = 0; mi < MI; mi++)
#pragma unroll
            for (int ni = 0; ni < NI; ni++)
                acc[mi][ni] = __builtin_amdgcn_mfma_f32_16x16x32_bf16(af[mi], bfr[ni], acc[mi][ni], 0, 0, 0);
        __syncthreads();
    }

    // ---- epilogue
#pragma unroll
    for (int mi = 0; mi < MI; mi++) {
#pragma unroll
        for (int ni = 0; ni < NI; ni++) {
#pragma unroll
            for (int r = 0; r < 4; r++) {
                int row = r0 + wr + mi * 16 + (lane >> 4) * 4 + r;
                int col = c0 + wc + ni * 16 + l15;
                float v = acc[mi][ni][r];
                if (bias) v += bias[col];
                if (act == 1) v = tanhf(v);
                if (rowscale) v *= rowscale[(row & 1023) * 63 + (row >> 10)];
                if (outBF16) ((u16*)Cout)[(long)row * ldc + col] = f2bf(v);
                else         ((float*)Cout)[(long)row * ldc + col] = v;
            }
        }
    }
}

// ---------------------------------------------------------------------------
// Fused gates MFMA GEMM + LSTM epilogue.
// A = concat(xl[. ,640] | h0[. ,256]) bf16. B = Wt_g [1024][896] bf16.
// Block: 128 rows x 32 cell-cols x 4 gates (128 gate-cols). Gate tiles go
// through LDS (bf16) so each thread can combine i/f/g/o for its cells.
// ---------------------------------------------------------------------------
__launch_bounds__(256)
__global__ void gates_mfma(const u16* __restrict__ xl, const u16* __restrict__ h0,
                           const u16* __restrict__ Wt_g,
                           const float* __restrict__ b_ih, const float* __restrict__ b_hh,
                           const float* __restrict__ Cprev,
                           u16* __restrict__ Hbuf, float* __restrict__ Cbuf,
                           int offCur, int offPrev, int Ktot)
{
    constexpr int LDT = 40;
    __shared__ u16 smem[128 * 136];               // max(As+Bs = 10240, Gs = 17408) shorts
    __shared__ float bias_s[4][32];
    u16* As = smem;
    u16* Bs = smem + 128 * LDT;
    u16* Gs = smem;

    const int tid = threadIdx.x;
    const int lane = tid & 63, wv = tid >> 6;
    const int r0 = blockIdx.x * 128;
    const int by32 = blockIdx.y * 32;
    const int wr = (wv & 1) * 64, wc = (wv >> 1) * 64;
    const int l15 = lane & 15, q8 = (lane >> 4) * 8;

    if (tid < 128) {
        int g = tid >> 5, c = tid & 31;
        int gcol = g * 256 + by32 + c;
        bias_s[g][c] = b_ih[gcol] + b_hh[gcol];
    }

    f32x4 acc[4][4];
#pragma unroll
    for (int i = 0; i < 4; i++)
#pragma unroll
        for (int j = 0; j < 4; j++) acc[i][j] = (f32x4){0.f, 0.f, 0.f, 0.f};

    for (int kt = 0; kt < Ktot; kt += 32) {
        // stage A: concat(xl | h0)
#pragma unroll
        for (int p = 0; p < 2; p++) {
            int v = tid + p * 256;
            int row = v >> 2, kc = (v & 3) * 8;
            long ar = r0 + row;
            int k = kt + kc;
            int4 val;
            if (k < 640) val = *(const int4*)(xl + ar * 640L + k);
            else         val = *(const int4*)(h0 + ar * 256L + (k - 640));
            *(int4*)&As[row * LDT + kc] = val;
        }
        // stage B: LDS row j = gate (j>>5), cell (j&31)
#pragma unroll
        for (int p = 0; p < 2; p++) {
            int v = tid + p * 256;
            int row = v >> 2, kc = (v & 3) * 8;
            long brow = (long)((row >> 5) * 256 + by32 + (row & 31));
            *(int4*)&Bs[row * LDT + kc] = *(const int4*)(Wt_g + brow * 896 + kt + kc);
        }
        __syncthreads();

        bf16x8 af[4], bfr[4];
#pragma unroll
        for (int mi = 0; mi < 4; mi++)
            af[mi] = *reinterpret_cast<const bf16x8*>(&As[(wr + mi * 16 + l15) * LDT + q8]);
#pragma unroll
        for (int ni = 0; ni < 4; ni++)
            bfr[ni] = *reinterpret_cast<const bf16x8*>(&Bs[(wc + ni * 16 + l15) * LDT + q8]);
#pragma unroll
        for (int mi = 0; mi < 4; mi++)
#pragma unroll
            for (int ni = 0; ni < 4; ni++)
                acc[mi][ni] = __builtin_amdgcn_mfma_f32_16x16x32_bf16(af[mi], bfr[ni], acc[mi][ni], 0, 0, 0);
        __syncthreads();
    }

    // dump gate tiles to LDS (aliases As/Bs; all reads drained by loop-end barrier)
#pragma unroll
    for (int mi = 0; mi < 4; mi++)
#pragma unroll
        for (int ni = 0; ni < 4; ni++)
#pragma unroll
            for (int r = 0; r < 4; r++) {
                int lr = wr + mi * 16 + (lane >> 4) * 4 + r;
                int lc = wc + ni * 16 + l15;
                Gs[lr * 136 + lc] = f2bf(acc[mi][ni][r]);
            }
    __syncthreads();

    // LSTM combine: 16 (row, cell) pairs per thread
#pragma unroll
    for (int i = 0; i < 16; i++) {
        int r = (tid >> 5) * 16 + i;
        int c = tid & 31;
        float iv = b2f(Gs[r * 136 + c])      + bias_s[0][c];
        float fv = b2f(Gs[r * 136 + 32 + c]) + bias_s[1][c];
        float gv = b2f(Gs[r * 136 + 64 + c]) + bias_s[2][c];
        float ov = b2f(Gs[r * 136 + 96 + c]) + bias_s[3][c];
        int rloc = r0 + r;
        int nd = rloc >> 10, bb = rloc & 1023;
        int gcol = by32 + c;
        float c0v = 0.f;
        if (Cprev) {
            long ch = ((long)(offPrev + nd * 2) * 1024 + bb) * 256 + gcol;
            c0v = 0.5f * (Cprev[ch] + Cprev[ch + 262144]);
        }
        float cv = sigf(fv) * c0v + sigf(iv) * tanhf(gv);
        float hv = sigf(ov) * tanhf(cv);
        long orow = ((long)offCur * 1024 + rloc) * 256 + gcol;
        Cbuf[orow] = cv;
        Hbuf[orow] = f2bf(hv);
    }
}

// ---------------------------------------------------------------------------
// Attention logits: one wave per descendant row (global node g < off).
// ---------------------------------------------------------------------------
__launch_bounds__(256)
__global__ void attn_logits(const float* __restrict__ E, const float* __restrict__ xextall,
                            const float* __restrict__ W_a, float* __restrict__ Lbuf,
                            int level, int rows, int m, int off)
{
    const int wv = threadIdx.x >> 6, ln = threadIdx.x & 63;
    const long dr = (long)blockIdx.x * 4 + wv;
    if (dr >= rows) return;
    const int g = (int)(dr >> 10), bb = (int)(dr & 1023);
    int lp, node;
    if      (g < 32) { lp = 0; node = g;      }
    else if (g < 48) { lp = 1; node = g - 32; }
    else if (g < 56) { lp = 2; node = g - 48; }
    else if (g < 60) { lp = 3; node = g - 56; }
    else             { lp = 4; node = g - 60; }
    const int shift  = level - lp;
    const int i      = node >> shift;
    const int within = node & ((1 << shift) - 1);
    const int d      = ((2 << level) - (2 << shift)) + within;

    float e = E[dr * 64 + ln] + xextall[((long)(off + i) * 1024 + bb) * 64 + ln];
    float v = tanhf(e) * W_a[ln];
#pragma unroll
    for (int s = 32; s; s >>= 1) v += __shfl_xor(v, s);
    if (ln == 0) Lbuf[((long)(i * m + d)) * 1024 + bb] = v;
}

// ---------------------------------------------------------------------------
// Softmax + pooling. One block per (i, b). Hbuf is bf16, global-node rows.
// ---------------------------------------------------------------------------
__launch_bounds__(256)
__global__ void attn_pool(const float* __restrict__ Lbuf, const u16* __restrict__ Hbuf,
                          float* __restrict__ pooled, int level, int m)
{
    const int blk = blockIdx.x;            // i*1024 + b
    const int i = blk >> 10, bb = blk & 1023;
    const int tid = threadIdx.x;
    __shared__ float raw[64];
    __shared__ float wsm[64];
    if (tid < m) raw[tid] = Lbuf[((long)(i * m + tid)) * 1024 + bb];
    __syncthreads();
    if (tid == 0) {
        float mx = -1e30f;
        for (int d = 0; d < m; d++) mx = fmaxf(mx, raw[d]);
        float s = 0.f;
        for (int d = 0; d < m; d++) { float e = expf(raw[d] - mx); wsm[d] = e; s += e; }
        float inv = 1.f / s;
        for (int d = 0; d < m; d++) wsm[d] *= inv;
    }
    __syncthreads();
    float accv = 0.f;
    const int h = tid;
    int cum = 0;
    for (int lp = 0; lp < level; lp++) {
        int sz = 1 << (level - lp);
        int base = 64 - (64 >> lp);
        for (int q = 0; q < sz; q++) {
            long row = (long)(base + i * sz + q) * 1024 + bb;
            accv = fmaf(wsm[cum + q], b2f(Hbuf[row * 256 + h]), accv);
        }
        cum += sz;
    }
    pooled[(long)blk * 256 + h] = accv;
}

// ---------------------------------------------------------------------------
// Output heads. One block per batch b; Hbuf root row is bf16.
// ---------------------------------------------------------------------------
__launch_bounds__(256)
__global__ void heads_kernel(const u16* __restrict__ Hbuf,
                             const float* __restrict__ W_c1, const float* __restrict__ b_c1,
                             const float* __restrict__ W_c2, const float* __restrict__ b_c2,
                             const float* __restrict__ W_c3, const float* __restrict__ b_c3,
                             const float* __restrict__ W_d1, const float* __restrict__ b_d1,
                             const float* __restrict__ W_d2, const float* __restrict__ b_d2,
                             const float* __restrict__ W_d3, const float* __restrict__ b_d3,
                             float* __restrict__ out)
{
    const int bb = blockIdx.x, tid = threadIdx.x;
    __shared__ float root[256];
    __shared__ float t1[128];
    __shared__ float t2[128];
    __shared__ float red[256];
    root[tid] = b2f(Hbuf[((long)62 * 1024 + bb) * 256 + tid]);
    __syncthreads();
    for (int head = 0; head < 2; head++) {
        const float* w1  = head ? W_d1 : W_c1;
        const float* bi1 = head ? b_d1 : b_c1;
        const float* w2  = head ? W_d2 : W_c2;
        const float* bi2 = head ? b_d2 : b_c2;
        const float* w3  = head ? W_d3 : W_c3;
        const float* bi3 = head ? b_d3 : b_c3;
        if (tid < 128) {
            float s = bi1[tid];
            for (int k = 0; k < 256; k++) s = fmaf(root[k], w1[k * 128 + tid], s);
            t1[tid] = fmaxf(s, 0.f);
        }
        __syncthreads();
        if (tid < 128) {
            float s = bi2[tid];
            for (int k = 0; k < 128; k++) s = fmaf(t1[k], w2[k * 128 + tid], s);
            t2[tid] = fmaxf(s, 0.f);
        }
        __syncthreads();
        red[tid] = (tid < 128) ? t2[tid] * w3[tid] : 0.f;
        __syncthreads();
        for (int s = 128; s; s >>= 1) { if (tid < s) red[tid] += red[tid + s]; __syncthreads(); }
        if (tid == 0) out[head * 1024 + bb] = sigf(red[0] + bi3[0]);
        __syncthreads();
    }
}

// ---------------------------------------------------------------------------
extern "C" void kernel_launch(void* const* d_in, const int* in_sizes, int n_in,
                              void* d_out, int out_size, void* d_ws, size_t ws_size,
                              hipStream_t stream)
{
    (void)in_sizes; (void)n_in; (void)out_size;
    const float* op       = (const float*)d_in[0];
    const float* feat     = (const float*)d_in[1];
    const float* cond1    = (const float*)d_in[2];
    const float* cond2    = (const float*)d_in[3];
    const float* bitmap   = (const float*)d_in[4];
    const float* has_cond = (const float*)d_in[5];
    const float* W_op     = (const float*)d_in[6];
    const float* b_op     = (const float*)d_in[7];
    const float* W_feat   = (const float*)d_in[8];
    const float* b_feat   = (const float*)d_in[9];
    const float* W_pred   = (const float*)d_in[10];
    const float* b_pred   = (const float*)d_in[11];
    const float* W_bm     = (const float*)d_in[12];
    const float* b_bm     = (const float*)d_in[13];
    const float* W_ih     = (const float*)d_in[14];
    const float* b_ih     = (const float*)d_in[15];
    const float* W_hh     = (const float*)d_in[16];
    const float* b_hh     = (const float*)d_in[17];
    const float* W_wh     = (const float*)d_in[18];
    const float* W_ext    = (const float*)d_in[19];
    const float* W_a      = (const float*)d_in[20];
    const float* W_ht     = (const float*)d_in[21];
    const float* b_ht     = (const float*)d_in[22];
    const float* W_c1     = (const float*)d_in[23];
    const float* b_c1     = (const float*)d_in[24];
    const float* W_c2     = (const float*)d_in[25];
    const float* b_c2     = (const float*)d_in[26];
    const float* W_c3     = (const float*)d_in[27];
    const float* b_c3     = (const float*)d_in[28];
    const float* W_d1     = (const float*)d_in[29];
    const float* b_d1     = (const float*)d_in[30];
    const float* W_d2     = (const float*)d_in[31];
    const float* b_d2     = (const float*)d_in[32];
    const float* W_d3     = (const float*)d_in[33];
    const float* b_d3     = (const float*)d_in[34];
    float* out = (float*)d_out;

    // workspace layout, node-major rows: row = node_global*1024 + b
    char* p = (char*)d_ws;
    auto alloc = [&](size_t bytes) -> char* {
        char* r = p; p += (bytes + 255) & ~(size_t)255; return r;
    };
    u16*   xall    = (u16*)  alloc((size_t)64512 * 640 * 2);   // bf16 x, all 63 nodes
    float* xextall = (float*)alloc((size_t)64512 * 64 * 4);    // x @ W_ext
    u16*   Hbuf    = (u16*)  alloc((size_t)64512 * 256 * 2);   // hiddens (bf16)
    float* Cbuf    = (float*)alloc((size_t)64512 * 256 * 4);   // cells (f32)
    float* Ebuf    = (float*)alloc((size_t)62 * 1024 * 64 * 4);// H @ W_wh
    float* pooled  = (float*)alloc((size_t)16384 * 256 * 4);
    u16*   h0      = (u16*)  alloc((size_t)16384 * 256 * 2);
    float* Lbuf    = (float*)alloc((size_t)65536 * 4);
    u16*   Wt_op   = (u16*)  alloc((size_t)128 * 32 * 2);
    u16*   Wt_feat = (u16*)  alloc((size_t)128 * 64 * 2);
    u16*   Wt_pred = (u16*)  alloc((size_t)128 * 256 * 2);
    u16*   Wt_bm   = (u16*)  alloc((size_t)128 * 1024 * 2);
    u16*   Wt_g    = (u16*)  alloc((size_t)1024 * 896 * 2);
    u16*   Wt_wh   = (u16*)  alloc((size_t)64 * 256 * 2);
    u16*   Wt_ext  = (u16*)  alloc((size_t)64 * 640 * 2);
    u16*   Wt_ht   = (u16*)  alloc((size_t)256 * 256 * 2);
    if (ws_size < (size_t)(p - (char*)d_ws)) return;

    // ---- weight prep (bf16, [N][K] with K zero-padded to x32)
    prep_w<<<16,  256, 0, stream>>>(W_op,   Wt_op,   32,   128, 32);
    prep_w<<<32,  256, 0, stream>>>(W_feat, Wt_feat, 64,   128, 64);
    prep_w<<<128, 256, 0, stream>>>(W_pred, Wt_pred, 256,  128, 256);
    prep_w<<<512, 256, 0, stream>>>(W_bm,   Wt_bm,   1000, 128, 1024);
    prep_w<<<64,  256, 0, stream>>>(W_wh,   Wt_wh,   256,  64,  256);
    prep_w<<<160, 256, 0, stream>>>(W_ext,  Wt_ext,  640,  64,  640);
    prep_w<<<256, 256, 0, stream>>>(W_ht,   Wt_ht,   256,  256, 256);
    prep_g<<<3584,256, 0, stream>>>(W_ih, W_hh, Wt_g);

    // ---- x projections for ALL 63 nodes at once (M = 64512 = 504*128)
    gemm_bf16<true,128><<<dim3(504,1), 256, 0, stream>>>(op,     Wt_op,   (void*)(xall + 0),   b_op,   nullptr,  32,   32,   32,   640, 1, 0, 1);
    gemm_bf16<true,128><<<dim3(504,1), 256, 0, stream>>>(feat,   Wt_feat, (void*)(xall + 128), b_feat, nullptr,  64,   64,   64,   640, 1, 0, 1);
    gemm_bf16<true,128><<<dim3(504,1), 256, 0, stream>>>(cond1,  Wt_pred, (void*)(xall + 256), b_pred, nullptr,  256,  256,  256,  640, 1, 0, 1);
    gemm_bf16<true,128><<<dim3(504,1), 256, 0, stream>>>(cond2,  Wt_pred, (void*)(xall + 384), b_pred, nullptr,  256,  256,  256,  640, 1, 0, 1);
    gemm_bf16<true,128><<<dim3(504,1), 256, 0, stream>>>(bitmap, Wt_bm,   (void*)(xall + 512), b_bm,   has_cond, 1000, 1024, 1000, 640, 1, 0, 1);
    // xext for all nodes
    gemm_bf16<false,64><<<dim3(504,1), 256, 0, stream>>>(xall, Wt_ext, (void*)xextall, nullptr, nullptr, 640, 640, 640, 64, 0, 0, 0);

    for (int l = 0; l < 6; l++) {
        const int n   = 32 >> l;
        const int off = 64 - (64 >> l);     // OFFSETS[l] = global node base
        const int M   = n * 1024;
        const int m   = (2 << l) - 2;

        if (l > 0) {
            int rows = off * 1024;
            attn_logits<<<rows / 4, 256, 0, stream>>>(Ebuf, xextall, W_a, Lbuf, l, rows, m, off);
            attn_pool<<<M, 256, 0, stream>>>(Lbuf, Hbuf, pooled, l, m);
            gemm_bf16<true,128><<<dim3(M/128, 2), 256, 0, stream>>>(pooled, Wt_ht, (void*)h0, b_ht, nullptr, 256, 256, 256, 256, 0, 1, 1);
        }

        const int Ktot    = l ? 896 : 640;
        const int offPrev = l ? (64 - (64 >> (l - 1))) : 0;
        gates_mfma<<<dim3(M/128, 8), 256, 0, stream>>>(xall + (size_t)off * 1024 * 640, h0, Wt_g,
                                                       b_ih, b_hh, l ? Cbuf : nullptr,
                                                       Hbuf, Cbuf, off, offPrev, Ktot);

        if (l < 5) {
            gemm_bf16<false,64><<<dim3(M/128, 1), 256, 0, stream>>>(Hbuf + (size_t)off * 1024 * 256, Wt_wh,
                                                                    (void*)(Ebuf + (size_t)off * 1024 * 64),
                                                                    nullptr, nullptr, 256, 256, 256, 64, 0, 0, 0);
        }
    }

    heads_kernel<<<1024, 256, 0, stream>>>(Hbuf, W_c1, b_c1, W_c2, b_c2, W_c3, b_c3,
                                           W_d1, b_d1, W_d2, b_d2, W_d3, b_d3, out);
}